// Round 2
// baseline (1420.638 us; speedup 1.0000x reference)
//
#include <hip/hip_runtime.h>
#include <hip/hip_bf16.h>
#include <stdint.h>

// Problem constants (fixed shape): B=16, L=65536, H=64, K=64
#define LCOUNT 65536
#define LOUT   65473   // L - (H-1)
#define KF     64
#define HH     64
#define TL     256     // output positions per block

typedef __attribute__((ext_vector_type(8))) short  short8;   // 8 bf16 (4 VGPRs)
typedef __attribute__((ext_vector_type(4))) float  float4v;  // 4 fp32

__device__ __forceinline__ unsigned short f2bf(float f) {
    union { float f; uint32_t u; } c; c.f = f;
    uint32_t u = c.u;
    u += 0x7FFFu + ((u >> 16) & 1u);   // round-to-nearest-even
    return (unsigned short)(u >> 16);
}

__global__ __launch_bounds__(256)
void hankel_kernel(const float* __restrict__ x,
                   const float* __restrict__ W,
                   const float* __restrict__ bias,
                   float* __restrict__ out)
{
    __shared__ float          xs_f[TL + 64];
    __shared__ unsigned short xs_b[TL + 64];
    __shared__ float          mu_s[TL];
    __shared__ float          inv_s[TL];

    const int tid  = threadIdx.x;
    const int lane = tid & 63;
    const int wv   = tid >> 6;
    const int m    = lane & 15;   // A-row (filter sub-idx) AND C/D col (position)
    const int quad = lane >> 4;

    const int tile     = blockIdx.x;
    const int bb       = blockIdx.y;
    const int block_lo = tile * TL;

    // ---- stage x tile: fp32 (for stats) + bf16 (for MFMA B) ----
    const float* xrow = x + (size_t)bb * LCOUNT;
    for (int i = tid; i < TL + 64; i += 256) {
        int gi = block_lo + i;
        if (gi > LCOUNT - 1) gi = LCOUNT - 1;   // tail clamp; masked at store
        float v = xrow[gi];
        xs_f[i] = v;
        xs_b[i] = f2bf(v);
    }

    // ---- A fragments (W): afrag[t][ki] -> A[m=lane&15][h=quad*8+j+32*ki], filter k=t*16+m ----
    short8 afrag[4][2];
    #pragma unroll
    for (int t = 0; t < 4; ++t) {
        const int k = t * 16 + m;
        #pragma unroll
        for (int ki = 0; ki < 2; ++ki) {
            const float4v* wp = (const float4v*)(W + k * HH + quad * 8 + ki * 32);
            float4v w0 = wp[0];
            float4v w1 = wp[1];
            short8 f;
            f[0] = (short)f2bf(w0[0]); f[1] = (short)f2bf(w0[1]);
            f[2] = (short)f2bf(w0[2]); f[3] = (short)f2bf(w0[3]);
            f[4] = (short)f2bf(w1[0]); f[5] = (short)f2bf(w1[1]);
            f[6] = (short)f2bf(w1[2]); f[7] = (short)f2bf(w1[3]);
            afrag[t][ki] = f;
        }
    }

    // ---- per-thread epilogue constants: filters kf = t*16 + quad*4 + r ----
    float wsumr[4][4], biasr[4][4];
    #pragma unroll
    for (int t = 0; t < 4; ++t) {
        #pragma unroll
        for (int r = 0; r < 4; ++r) {
            const int kf = t * 16 + quad * 4 + r;
            const float* wr = W + kf * HH;
            float s = 0.f;
            #pragma unroll
            for (int h = 0; h < HH; ++h) s += wr[h];   // L2/L1-hot, 16 KB total
            wsumr[t][r] = s;
            biasr[t][r] = bias[kf];
        }
    }

    __syncthreads();

    // ---- per-position window stats (one position per thread) ----
    {
        const int p = tid;
        float s1 = 0.f, s2 = 0.f;
        #pragma unroll 8
        for (int j = 0; j < HH; ++j) {
            float v = xs_f[p + j];
            s1 += v;
            s2 += v * v;
        }
        float mu  = s1 * (1.f / 64.f);
        float var = (s2 - 64.f * mu * mu) * (1.f / 63.f);
        var = var < 0.f ? 0.f : var;
        float sd  = sqrtf(var);
        mu_s[p]  = mu;
        inv_s[p] = 1.f / (sd + 1e-6f);
    }
    __syncthreads();

    // ---- MFMA phase: each wave handles groups of 16 positions ----
    for (int g = wv; g < TL / 16; g += 4) {
        const int p0    = g * 16;
        const int abase = p0 + m + quad * 8;   // B[k=quad*8+j][n=m] = xs[p0+m+k]

        short8 b0, b1;
        #pragma unroll
        for (int j = 0; j < 8; ++j) {
            b0[j] = (short)xs_b[abase + j];
            b1[j] = (short)xs_b[abase + 32 + j];
        }

        // per-lane position stats (C/D col = m)
        const float muv  = mu_s[p0 + m];
        const float invv = inv_s[p0 + m];
        const int   lo   = block_lo + p0 + m;

        float4v acc[4];
        #pragma unroll
        for (int t = 0; t < 4; ++t) acc[t] = (float4v){0.f, 0.f, 0.f, 0.f};

        #pragma unroll
        for (int t = 0; t < 4; ++t) {
            acc[t] = __builtin_amdgcn_mfma_f32_16x16x32_bf16(afrag[t][0], b0, acc[t], 0, 0, 0);
            acc[t] = __builtin_amdgcn_mfma_f32_16x16x32_bf16(afrag[t][1], b1, acc[t], 0, 0, 0);
        }

        // ---- epilogue: fold layernorm + bias + relu; contiguous dwordx4 stores ----
        if (lo < LOUT) {
            float* op = out + ((size_t)bb * LOUT + lo) * KF + quad * 4;
            #pragma unroll
            for (int t = 0; t < 4; ++t) {
                float4v v;
                #pragma unroll
                for (int r = 0; r < 4; ++r) {
                    float vv = (acc[t][r] - muv * wsumr[t][r]) * invv + biasr[t][r];
                    v[r] = vv > 0.f ? vv : 0.f;
                }
                *(float4v*)(op + t * 16) = v;
            }
        }
    }

    // ---- output 1: warmup scalar = 63 ----
    if (tile == 0 && bb == 0 && tid == 0) {
        out[(size_t)16 * LOUT * KF] = 63.0f;
    }
}

extern "C" void kernel_launch(void* const* d_in, const int* in_sizes, int n_in,
                              void* d_out, int out_size, void* d_ws, size_t ws_size,
                              hipStream_t stream) {
    const float* x = (const float*)d_in[0];   // (16, 65536) fp32
    const float* W = (const float*)d_in[1];   // (64, 64) fp32
    const float* b = (const float*)d_in[2];   // (64,) fp32
    float* out = (float*)d_out;               // 16*65473*64 fp32 + 1 (warmup)

    dim3 grid((LOUT + TL - 1) / TL, 16);      // 256 tiles x 16 batches
    hankel_kernel<<<grid, 256, 0, stream>>>(x, W, b, out);
}

// Round 3
// 300.577 us; speedup vs baseline: 4.7264x; 4.7264x over previous
//
#include <hip/hip_runtime.h>
#include <hip/hip_bf16.h>
#include <stdint.h>

// Problem constants (fixed shape): B=16, L=65536, H=64, K=64
#define LCOUNT 65536
#define LOUT   65473   // L - (H-1)
#define KF     64
#define HH     64
#define TL     256     // output positions per block

typedef __attribute__((ext_vector_type(8))) short  short8;   // 8 bf16 (4 VGPRs)
typedef __attribute__((ext_vector_type(4))) float  float4v;  // 4 fp32

__device__ __forceinline__ unsigned short f2bf(float f) {
    union { float f; uint32_t u; } c; c.f = f;
    uint32_t u = c.u;
    u += 0x7FFFu + ((u >> 16) & 1u);   // round-to-nearest-even
    return (unsigned short)(u >> 16);
}

__global__ __launch_bounds__(256)
void hankel_kernel(const float* __restrict__ x,
                   const float* __restrict__ W,
                   const float* __restrict__ bias,
                   float* __restrict__ out)
{
    __shared__ float          xs_f[TL + 64];
    __shared__ unsigned short xs_b[TL + 64];
    __shared__ float          mu_s[TL];
    __shared__ float          inv_s[TL];
    __shared__ float          wsum_s[KF];
    __shared__ float          bias_s[KF];

    const int tid  = threadIdx.x;
    const int lane = tid & 63;
    const int wv   = tid >> 6;
    const int m    = lane & 15;   // A-row (filter sub-idx) AND C/D col (position)
    const int quad = lane >> 4;

    const int tile     = blockIdx.x;
    const int bb       = blockIdx.y;
    const int block_lo = tile * TL;

    // ---- stage x tile: fp32 (for stats) + bf16 (for MFMA B) ----
    const float* xrow = x + (size_t)bb * LCOUNT;
    for (int i = tid; i < TL + 64; i += 256) {
        int gi = block_lo + i;
        if (gi > LCOUNT - 1) gi = LCOUNT - 1;   // tail clamp; masked at store
        float v = xrow[gi];
        xs_f[i] = v;
        xs_b[i] = f2bf(v);
    }

    // ---- Wsum[k] and bias -> LDS (threads 0..63, vectorized; W is 16KB L2-hot) ----
    if (tid < KF) {
        const float4v* wr = (const float4v*)(W + tid * HH);
        float s = 0.f;
        #pragma unroll
        for (int i = 0; i < HH / 4; ++i) {
            float4v w = wr[i];
            s += w[0] + w[1] + w[2] + w[3];
        }
        wsum_s[tid] = s;
        bias_s[tid] = bias[tid];
    }

    // ---- A fragments (W): afrag[t][ki] -> A[m=lane&15][h=quad*8+j+32*ki], filter k=t*16+m ----
    short8 afrag[4][2];
    #pragma unroll
    for (int t = 0; t < 4; ++t) {
        const int k = t * 16 + m;
        #pragma unroll
        for (int ki = 0; ki < 2; ++ki) {
            const float4v* wp = (const float4v*)(W + k * HH + quad * 8 + ki * 32);
            float4v w0 = wp[0];
            float4v w1 = wp[1];
            short8 f;
            f[0] = (short)f2bf(w0[0]); f[1] = (short)f2bf(w0[1]);
            f[2] = (short)f2bf(w0[2]); f[3] = (short)f2bf(w0[3]);
            f[4] = (short)f2bf(w1[0]); f[5] = (short)f2bf(w1[1]);
            f[6] = (short)f2bf(w1[2]); f[7] = (short)f2bf(w1[3]);
            afrag[t][ki] = f;
        }
    }

    __syncthreads();

    // ---- per-position window stats (one position per thread) ----
    {
        const int p = tid;
        float s1 = 0.f, s2 = 0.f;
        #pragma unroll 8
        for (int j = 0; j < HH; ++j) {
            float v = xs_f[p + j];
            s1 += v;
            s2 += v * v;
        }
        float mu  = s1 * (1.f / 64.f);
        float var = (s2 - 64.f * mu * mu) * (1.f / 63.f);
        var = var < 0.f ? 0.f : var;
        float sd  = sqrtf(var);
        mu_s[p]  = mu;
        inv_s[p] = 1.f / (sd + 1e-6f);
    }
    __syncthreads();

    // ---- MFMA phase: each wave handles groups of 16 positions ----
    for (int g = wv; g < TL / 16; g += 4) {
        const int p0    = g * 16;
        const int abase = p0 + m + quad * 8;   // B[k=quad*8+j][n=m] = xs[p0+m+k]

        short8 b0, b1;
        #pragma unroll
        for (int j = 0; j < 8; ++j) {
            b0[j] = (short)xs_b[abase + j];
            b1[j] = (short)xs_b[abase + 32 + j];
        }

        // per-lane position stats (C/D col = m)
        const float muv  = mu_s[p0 + m];
        const float invv = inv_s[p0 + m];
        const int   lo   = block_lo + p0 + m;

        float4v acc[4];
        #pragma unroll
        for (int t = 0; t < 4; ++t) acc[t] = (float4v){0.f, 0.f, 0.f, 0.f};

        #pragma unroll
        for (int t = 0; t < 4; ++t) {
            acc[t] = __builtin_amdgcn_mfma_f32_16x16x32_bf16(afrag[t][0], b0, acc[t], 0, 0, 0);
            acc[t] = __builtin_amdgcn_mfma_f32_16x16x32_bf16(afrag[t][1], b1, acc[t], 0, 0, 0);
        }

        // ---- epilogue: fold layernorm + bias + relu; contiguous dwordx4 stores ----
        if (lo < LOUT) {
            float* op = out + ((size_t)bb * LOUT + lo) * KF + quad * 4;
            #pragma unroll
            for (int t = 0; t < 4; ++t) {
                // epilogue constants from LDS (conflict-free: addr depends on quad only)
                float4v ws = *(const float4v*)(wsum_s + t * 16 + quad * 4);
                float4v bs = *(const float4v*)(bias_s + t * 16 + quad * 4);
                float4v v;
                #pragma unroll
                for (int r = 0; r < 4; ++r) {
                    float vv = (acc[t][r] - muv * ws[r]) * invv + bs[r];
                    v[r] = vv > 0.f ? vv : 0.f;
                }
                *(float4v*)(op + t * 16) = v;
            }
        }
    }

    // ---- output 1: warmup scalar = 63 ----
    if (tile == 0 && bb == 0 && tid == 0) {
        out[(size_t)16 * LOUT * KF] = 63.0f;
    }
}

extern "C" void kernel_launch(void* const* d_in, const int* in_sizes, int n_in,
                              void* d_out, int out_size, void* d_ws, size_t ws_size,
                              hipStream_t stream) {
    const float* x = (const float*)d_in[0];   // (16, 65536) fp32
    const float* W = (const float*)d_in[1];   // (64, 64) fp32
    const float* b = (const float*)d_in[2];   // (64,) fp32
    float* out = (float*)d_out;               // 16*65473*64 fp32 + 1 (warmup)

    dim3 grid((LOUT + TL - 1) / TL, 16);      // 256 tiles x 16 batches
    hankel_kernel<<<grid, 256, 0, stream>>>(x, W, b, out);
}

// Round 4
// 282.893 us; speedup vs baseline: 5.0218x; 1.0625x over previous
//
#include <hip/hip_runtime.h>
#include <hip/hip_bf16.h>
#include <stdint.h>

// Problem constants (fixed shape): B=16, L=65536, H=64, K=64
#define LCOUNT 65536
#define LOUT   65473   // L - (H-1)
#define KF     64
#define HH     64
#define TL     1024    // output positions per block

typedef __attribute__((ext_vector_type(8))) short  short8;   // 8 bf16 (4 VGPRs)
typedef __attribute__((ext_vector_type(4))) float  float4v;  // 4 fp32

__device__ __forceinline__ unsigned short f2bf(float f) {
    union { float f; uint32_t u; } c; c.f = f;
    uint32_t u = c.u;
    u += 0x7FFFu + ((u >> 16) & 1u);   // round-to-nearest-even
    return (unsigned short)(u >> 16);
}

__global__ __launch_bounds__(256)
void hankel_kernel(const float* __restrict__ x,
                   const float* __restrict__ W,
                   const float* __restrict__ bias,
                   float* __restrict__ out)
{
    __shared__ float          xs_f[TL + 64];     // 4352 B
    __shared__ unsigned short xs_b[TL + 64];     // 2176 B
    __shared__ float          mu_s[TL];          // 4096 B
    __shared__ float          inv_s[TL];         // 4096 B
    __shared__ float          wsum_s[KF];
    __shared__ float          bias_s[KF];

    const int tid  = threadIdx.x;
    const int lane = tid & 63;
    const int wv   = tid >> 6;
    const int m    = lane & 15;   // A-row (filter sub-idx) AND C/D col (position)
    const int quad = lane >> 4;

    const int tile     = blockIdx.x;
    const int bb       = blockIdx.y;
    const int block_lo = tile * TL;

    // ---- stage x tile (float4 loads): fp32 for stats + packed bf16 for MFMA ----
    {
        const float4v* xrow4 = (const float4v*)(x + (size_t)bb * LCOUNT);
        const int base4 = block_lo >> 2;           // block_lo % 4 == 0
        const int nf4   = (TL + 64) / 4;           // 272
        for (int i4 = tid; i4 < nf4; i4 += 256) {
            int g4 = base4 + i4;
            if (g4 > LCOUNT / 4 - 1) g4 = LCOUNT / 4 - 1;  // tail clamp; masked at store
            float4v v = xrow4[g4];
            *(float4v*)(xs_f + 4 * i4) = v;
            uint32_t plo = (uint32_t)f2bf(v[0]) | ((uint32_t)f2bf(v[1]) << 16);
            uint32_t phi = (uint32_t)f2bf(v[2]) | ((uint32_t)f2bf(v[3]) << 16);
            uint2* dst = (uint2*)(xs_b + 4 * i4);
            *dst = make_uint2(plo, phi);
        }
    }

    // ---- Wsum[k] and bias -> LDS (threads 0..63; W is 16KB L1/L2-hot) ----
    if (tid < KF) {
        const float4v* wr = (const float4v*)(W + tid * HH);
        float s = 0.f;
        #pragma unroll
        for (int i = 0; i < HH / 4; ++i) {
            float4v w = wr[i];
            s += w[0] + w[1] + w[2] + w[3];
        }
        wsum_s[tid] = s;
        bias_s[tid] = bias[tid];
    }

    // ---- A fragments (W): afrag[t][ki] -> A[m=lane&15][h=quad*8+j+32*ki], filter k=t*16+m ----
    short8 afrag[4][2];
    #pragma unroll
    for (int t = 0; t < 4; ++t) {
        const int k = t * 16 + m;
        #pragma unroll
        for (int ki = 0; ki < 2; ++ki) {
            const float4v* wp = (const float4v*)(W + k * HH + quad * 8 + ki * 32);
            float4v w0 = wp[0];
            float4v w1 = wp[1];
            short8 f;
            f[0] = (short)f2bf(w0[0]); f[1] = (short)f2bf(w0[1]);
            f[2] = (short)f2bf(w0[2]); f[3] = (short)f2bf(w0[3]);
            f[4] = (short)f2bf(w1[0]); f[5] = (short)f2bf(w1[1]);
            f[6] = (short)f2bf(w1[2]); f[7] = (short)f2bf(w1[3]);
            afrag[t][ki] = f;
        }
    }

    __syncthreads();

    // ---- window stats: thread owns 4 consecutive positions p0 = 4*tid .. +3 ----
    {
        const int p0 = 4 * tid;
        const float4v* xv = (const float4v*)(xs_f + p0);   // 16B aligned
        float s1 = 0.f, s2 = 0.f;
        float4v v0 = xv[0];
        float4v v16 = xv[16];
        #pragma unroll
        for (int i = 0; i < 16; ++i) {
            float4v v = xv[i];
            s1 += v[0] + v[1] + v[2] + v[3];
            s2 += v[0] * v[0] + v[1] * v[1] + v[2] * v[2] + v[3] * v[3];
        }
        float4v muv, invv;
        #pragma unroll
        for (int i = 0; i < 4; ++i) {
            if (i > 0) {
                float xo = v0[i - 1], xn = v16[i - 1];   // slide window by 1
                s1 += xn - xo;
                s2 += xn * xn - xo * xo;
            }
            float mu  = s1 * (1.f / 64.f);
            float var = (s2 - 64.f * mu * mu) * (1.f / 63.f);
            var = var < 0.f ? 0.f : var;
            muv[i]  = mu;
            invv[i] = 1.f / (sqrtf(var) + 1e-6f);
        }
        *(float4v*)(mu_s + p0)  = muv;
        *(float4v*)(inv_s + p0) = invv;
    }
    __syncthreads();

    // ---- MFMA phase: 16 position-groups per wave ----
    for (int g = wv; g < TL / 16; g += 4) {
        const int p0    = g * 16;
        const int abase = p0 + m + quad * 8;   // B[k=quad*8+j][n=m] = xs[p0+m+k]

        short8 b0, b1;
        #pragma unroll
        for (int j = 0; j < 8; ++j) {
            b0[j] = (short)xs_b[abase + j];
            b1[j] = (short)xs_b[abase + 32 + j];
        }

        // per-lane position stats (C/D col = m)
        const float muv  = mu_s[p0 + m];
        const float invv = inv_s[p0 + m];
        const int   lo   = block_lo + p0 + m;

        float4v acc[4];
        #pragma unroll
        for (int t = 0; t < 4; ++t) acc[t] = (float4v){0.f, 0.f, 0.f, 0.f};

        #pragma unroll
        for (int t = 0; t < 4; ++t) {
            acc[t] = __builtin_amdgcn_mfma_f32_16x16x32_bf16(afrag[t][0], b0, acc[t], 0, 0, 0);
            acc[t] = __builtin_amdgcn_mfma_f32_16x16x32_bf16(afrag[t][1], b1, acc[t], 0, 0, 0);
        }

        // ---- epilogue: fold layernorm + bias + relu; dwordx4 stores ----
        if (lo < LOUT) {
            float* op = out + ((size_t)bb * LOUT + lo) * KF + quad * 4;
            #pragma unroll
            for (int t = 0; t < 4; ++t) {
                // LDS broadcast reads (addr depends on quad,t only -> conflict-free)
                float4v ws = *(const float4v*)(wsum_s + t * 16 + quad * 4);
                float4v bs = *(const float4v*)(bias_s + t * 16 + quad * 4);
                float4v v;
                #pragma unroll
                for (int r = 0; r < 4; ++r) {
                    float vv = (acc[t][r] - muv * ws[r]) * invv + bs[r];
                    v[r] = vv > 0.f ? vv : 0.f;
                }
                *(float4v*)(op + t * 16) = v;
            }
        }
    }

    // ---- output 1: warmup scalar = 63 ----
    if (tile == 0 && bb == 0 && tid == 0) {
        out[(size_t)16 * LOUT * KF] = 63.0f;
    }
}

extern "C" void kernel_launch(void* const* d_in, const int* in_sizes, int n_in,
                              void* d_out, int out_size, void* d_ws, size_t ws_size,
                              hipStream_t stream) {
    const float* x = (const float*)d_in[0];   // (16, 65536) fp32
    const float* W = (const float*)d_in[1];   // (64, 64) fp32
    const float* b = (const float*)d_in[2];   // (64,) fp32
    float* out = (float*)d_out;               // 16*65473*64 fp32 + 1 (warmup)

    dim3 grid((LOUT + TL - 1) / TL, 16);      // 64 tiles x 16 batches
    hankel_kernel<<<grid, 256, 0, stream>>>(x, W, b, out);
}